// Round 3
// baseline (413.400 us; speedup 1.0000x reference)
//
#include <hip/hip_runtime.h>

// RGCN layer, MI355X. Round 3:
//   ws: A[N][768] bf16 (C0|C1|Xbf), Bt[256][768] bf16, cnt[N], edgebuf[N][32]
//   K1 prep:  fused { conv_x (blocks 0..24999), build_bt (25000..25767),
//                     build_edges (25768..28892) }
//   K2 agg:   2 dsts per wave (32 lanes x 16B gathers), ballot degrees
//   K3 gemm:  128x256 tile, MFMA 32x32x16, fragment-ordered LDS staging via
//             global_load_lds(16B) -> all ds_read_b128 are lane-linear
//             (zero bank conflicts); fused bias+LayerNorm+ReLU

#define NN 100000
#define NR 4
#define NE 200000
#define KDIM 768
#define CAP 32
#define BM 128

typedef __attribute__((ext_vector_type(8))) short short8;
typedef __attribute__((ext_vector_type(16))) float floatx16;

__device__ __forceinline__ unsigned short f2bf(float f) {
  unsigned u = __float_as_uint(f);
  u += 0x7FFFu + ((u >> 16) & 1u);
  return (unsigned short)(u >> 16);
}

__device__ __forceinline__ void gload16(const unsigned short* g, unsigned short* l) {
  __builtin_amdgcn_global_load_lds(
      (const __attribute__((address_space(1))) unsigned int*)g,
      (__attribute__((address_space(3))) unsigned int*)l, 16, 0, 0);
}

// ---------------- K1: fused prep ----------------
__global__ void prep(const float* __restrict__ x, const float* __restrict__ bases,
                     const float* __restrict__ loop_w, const int* __restrict__ src,
                     const int* __restrict__ dst, unsigned short* __restrict__ A,
                     unsigned short* __restrict__ Bt, int* __restrict__ cnt,
                     int* __restrict__ edgebuf) {
  const int b = blockIdx.x;
  const int tid = threadIdx.x;
  if (b < 25000) {
    // conv_x: x fp32 -> bf16 into A[:, 512:768)
    int q = b * 256 + tid;  // NN*64 quads exact
    int row = q >> 6;
    int c4 = (q & 63) << 2;
    const float4 v = *(const float4*)(x + (size_t)row * 256 + c4);
    ushort4 u;
    u.x = f2bf(v.x); u.y = f2bf(v.y); u.z = f2bf(v.z); u.w = f2bf(v.w);
    *(ushort4*)(A + (size_t)row * KDIM + 512 + c4) = u;
  } else if (b < 25768) {
    // build_bt: Bt[n][k] = {bases0, bases1, loop_w}^T in bf16
    int i = (b - 25000) * 256 + tid;  // 768*256 exact
    int n = i & 255;
    int k = i >> 8;
    float v;
    if (k < 256)      v = bases[k * 256 + n];
    else if (k < 512) v = bases[65536 + (k - 256) * 256 + n];
    else              v = loop_w[(k - 512) * 256 + n];
    Bt[(size_t)n * KDIM + k] = f2bf(v);
  } else {
    // build_edges: bucket by dst, one atomic per edge
    int i = (b - 25768) * 256 + tid;  // 3125*256 = 800000 exact
    int r = i / NE;
    int s = src[i];
    int dd = dst[i];
    int pos = atomicAdd(&cnt[dd], 1);
    if (pos < CAP) edgebuf[dd * CAP + pos] = s | (r << 20);  // src<2^17, rel bits 20-21
  }
}

// ---------------- K2: aggregation, 2 dsts per wave, 16B/lane gathers ----------------
__global__ void agg_edges(const int* __restrict__ edgebuf, const int* __restrict__ cnt,
                          const float* __restrict__ w_comp, unsigned short* __restrict__ A) {
  const int tid = threadIdx.x;
  const int lane = tid & 63;
  const int wave = tid >> 6;
  const int half = lane >> 5;
  const int l31 = lane & 31;
  const int d = blockIdx.x * 8 + wave * 2 + half;  // 12500*8 = 100000 exact

  int cc = cnt[d]; cc = cc < CAP ? cc : CAP;
  int ev = 0;
  if (l31 < cc) ev = edgebuf[d * CAP + l31];  // coalesced 128B bucket read per half
  const int rl = ev >> 20;

  // per-relation degree for this half's dst via ballot
  unsigned long long b0 = __ballot((l31 < cc) && rl == 0);
  unsigned long long b1 = __ballot((l31 < cc) && rl == 1);
  unsigned long long b2 = __ballot((l31 < cc) && rl == 2);
  unsigned long long b3 = __ballot((l31 < cc) && rl == 3);
  const int sh = half << 5;
  float i0 = 1.0f / fmaxf((float)__popc((unsigned)(b0 >> sh)), 1.0f);
  float i1 = 1.0f / fmaxf((float)__popc((unsigned)(b1 >> sh)), 1.0f);
  float i2 = 1.0f / fmaxf((float)__popc((unsigned)(b2 >> sh)), 1.0f);
  float i3 = 1.0f / fmaxf((float)__popc((unsigned)(b3 >> sh)), 1.0f);
  float s00 = w_comp[0] * i0, s10 = w_comp[1] * i0;
  float s01 = w_comp[2] * i1, s11 = w_comp[3] * i1;
  float s02 = w_comp[4] * i2, s12 = w_comp[5] * i2;
  float s03 = w_comp[6] * i3, s13 = w_comp[7] * i3;

  float a0[8] = {0.f, 0.f, 0.f, 0.f, 0.f, 0.f, 0.f, 0.f};
  float a1[8] = {0.f, 0.f, 0.f, 0.f, 0.f, 0.f, 0.f, 0.f};
  const unsigned short* Xp = A + 512 + l31 * 8;  // this lane's 16B of the x panel
  const int selbase = lane & 32;

#define EDGE_W(v, w0, w1)                                            \
  int r_##w0 = (v) >> 20;                                            \
  float w0 = r_##w0 < 2 ? (r_##w0 == 0 ? s00 : s01)                  \
                        : (r_##w0 == 2 ? s02 : s03);                 \
  float w1 = r_##w0 < 2 ? (r_##w0 == 0 ? s10 : s11)                  \
                        : (r_##w0 == 2 ? s12 : s13);

#define ACC8(g, w0, w1)                                              \
  {                                                                  \
    float e0 = __uint_as_float((g).x << 16);                         \
    float e1 = __uint_as_float((g).x & 0xFFFF0000u);                 \
    float e2 = __uint_as_float((g).y << 16);                         \
    float e3 = __uint_as_float((g).y & 0xFFFF0000u);                 \
    float e4 = __uint_as_float((g).z << 16);                         \
    float e5 = __uint_as_float((g).z & 0xFFFF0000u);                 \
    float e6 = __uint_as_float((g).w << 16);                         \
    float e7 = __uint_as_float((g).w & 0xFFFF0000u);                 \
    a0[0] += (w0) * e0; a0[1] += (w0) * e1; a0[2] += (w0) * e2;      \
    a0[3] += (w0) * e3; a0[4] += (w0) * e4; a0[5] += (w0) * e5;      \
    a0[6] += (w0) * e6; a0[7] += (w0) * e7;                          \
    a1[0] += (w1) * e0; a1[1] += (w1) * e1; a1[2] += (w1) * e2;      \
    a1[3] += (w1) * e3; a1[4] += (w1) * e4; a1[5] += (w1) * e5;      \
    a1[6] += (w1) * e6; a1[7] += (w1) * e7;                          \
  }

  int i = 0;
  for (; i + 4 <= cc; i += 4) {
    int v0 = __shfl(ev, selbase + i);
    int v1 = __shfl(ev, selbase + i + 1);
    int v2 = __shfl(ev, selbase + i + 2);
    int v3 = __shfl(ev, selbase + i + 3);
    const uint4 g0 = *(const uint4*)(Xp + (size_t)(v0 & 0xFFFFF) * KDIM);
    const uint4 g1 = *(const uint4*)(Xp + (size_t)(v1 & 0xFFFFF) * KDIM);
    const uint4 g2 = *(const uint4*)(Xp + (size_t)(v2 & 0xFFFFF) * KDIM);
    const uint4 g3 = *(const uint4*)(Xp + (size_t)(v3 & 0xFFFFF) * KDIM);
    { EDGE_W(v0, w0a, w1a) ACC8(g0, w0a, w1a) }
    { EDGE_W(v1, w0b, w1b) ACC8(g1, w0b, w1b) }
    { EDGE_W(v2, w0c, w1c) ACC8(g2, w0c, w1c) }
    { EDGE_W(v3, w0d, w1d) ACC8(g3, w0d, w1d) }
  }
  for (; i < cc; ++i) {
    int v = __shfl(ev, selbase + i);
    const uint4 g = *(const uint4*)(Xp + (size_t)(v & 0xFFFFF) * KDIM);
    EDGE_W(v, w0, w1)
    ACC8(g, w0, w1)
  }

  uint4 o0, o1;
  o0.x = (unsigned)f2bf(a0[0]) | ((unsigned)f2bf(a0[1]) << 16);
  o0.y = (unsigned)f2bf(a0[2]) | ((unsigned)f2bf(a0[3]) << 16);
  o0.z = (unsigned)f2bf(a0[4]) | ((unsigned)f2bf(a0[5]) << 16);
  o0.w = (unsigned)f2bf(a0[6]) | ((unsigned)f2bf(a0[7]) << 16);
  o1.x = (unsigned)f2bf(a1[0]) | ((unsigned)f2bf(a1[1]) << 16);
  o1.y = (unsigned)f2bf(a1[2]) | ((unsigned)f2bf(a1[3]) << 16);
  o1.z = (unsigned)f2bf(a1[4]) | ((unsigned)f2bf(a1[5]) << 16);
  o1.w = (unsigned)f2bf(a1[6]) | ((unsigned)f2bf(a1[7]) << 16);
  *(uint4*)(A + (size_t)d * KDIM + l31 * 8) = o0;
  *(uint4*)(A + (size_t)d * KDIM + 256 + l31 * 8) = o1;
}

// ---------------- K3: GEMM + bias + LN + ReLU ----------------
// Fragment-ordered LDS: each gload16 stages exactly one (rows x k-half) MFMA
// fragment set at [seg][lane*16B], so every ds_read_b128 is base+lane*16B:
// banks 4i..4i+3 mod 32, 2 lanes/bank -> conflict-free (m136).
__launch_bounds__(256, 2)
__global__ void gemm_ln(const unsigned short* __restrict__ A, const unsigned short* __restrict__ Bt,
                        const float* __restrict__ h_bias, const float* __restrict__ gamma,
                        const float* __restrict__ beta, float* __restrict__ out) {
  __shared__ unsigned short As[4 * 2 * 512];  // [wave][kk][lane*8]  8 KB
  __shared__ unsigned short Bs[8 * 2 * 512];  // [t][kk][lane*8]    16 KB
  const int tid = threadIdx.x;
  const int wave = tid >> 6;
  const int lane = tid & 63;
  const int l31 = lane & 31;
  const int half = lane >> 5;
  const int m0 = blockIdx.x * BM;

  floatx16 acc[8];
#pragma unroll
  for (int t = 0; t < 8; ++t)
#pragma unroll
    for (int r = 0; r < 16; ++r) acc[t][r] = 0.0f;

  int arow = m0 + wave * 32 + l31;
  if (arow >= NN) arow = NN - 1;  // tail rows duplicate row NN-1; outputs guarded
  const unsigned short* gA = A + (size_t)arow * KDIM + half * 8;
  const unsigned short* gBa = Bt + (size_t)(wave * 64 + l31) * KDIM + half * 8;  // tile 2w
  const unsigned short* gBb = gBa + 32 * KDIM;                                   // tile 2w+1
  unsigned short* lA0 = As + (wave * 2 + 0) * 512 + lane * 8;
  unsigned short* lA1 = As + (wave * 2 + 1) * 512 + lane * 8;
  unsigned short* lB0 = Bs + ((wave * 2 + 0) * 2 + 0) * 512 + lane * 8;
  unsigned short* lB1 = Bs + ((wave * 2 + 0) * 2 + 1) * 512 + lane * 8;
  unsigned short* lB2 = Bs + ((wave * 2 + 1) * 2 + 0) * 512 + lane * 8;
  unsigned short* lB3 = Bs + ((wave * 2 + 1) * 2 + 1) * 512 + lane * 8;

  for (int k0 = 0; k0 < KDIM; k0 += 32) {
    gload16(gA + k0, lA0);
    gload16(gA + k0 + 16, lA1);
    gload16(gBa + k0, lB0);
    gload16(gBa + k0 + 16, lB1);
    gload16(gBb + k0, lB2);
    gload16(gBb + k0 + 16, lB3);
    __syncthreads();
#pragma unroll
    for (int kk = 0; kk < 2; ++kk) {
      short8 af = *(const short8*)(As + (wave * 2 + kk) * 512 + lane * 8);
#pragma unroll
      for (int t = 0; t < 8; ++t) {
        short8 bfr = *(const short8*)(Bs + (t * 2 + kk) * 512 + lane * 8);
        acc[t] = __builtin_amdgcn_mfma_f32_32x32x16_bf16(af, bfr, acc[t], 0, 0, 0);
      }
    }
    __syncthreads();
  }

  // epilogue: bias, LayerNorm over 256 cols, gamma/beta, ReLU
  float bcol[8], gc[8], bc[8];
#pragma unroll
  for (int t = 0; t < 8; ++t) {
    int col = t * 32 + l31;
    bcol[t] = h_bias[col];
    gc[t] = gamma[col];
    bc[t] = beta[col];
  }
#pragma unroll
  for (int t = 0; t < 8; ++t)
#pragma unroll
    for (int r = 0; r < 16; ++r) acc[t][r] += bcol[t];

  const int m_base = m0 + wave * 32;
#pragma unroll
  for (int r = 0; r < 16; ++r) {
    float s = 0.f, q = 0.f;
#pragma unroll
    for (int t = 0; t < 8; ++t) { float v = acc[t][r]; s += v; q += v * v; }
#pragma unroll
    for (int m = 16; m >= 1; m >>= 1) {
      s += __shfl_xor(s, m);
      q += __shfl_xor(q, m);
    }
    float mean = s * (1.0f / 256.0f);
    float var = q * (1.0f / 256.0f) - mean * mean;
    float rstd = rsqrtf(var + 1e-5f);
    int row = (r & 3) + ((r >> 2) << 3) + (half << 2);  // C/D layout, 32x32
    int grow = m_base + row;
    if (grow < NN) {
#pragma unroll
      for (int t = 0; t < 8; ++t) {
        float v = (acc[t][r] - mean) * rstd * gc[t] + bc[t];
        out[(size_t)grow * 256 + t * 32 + l31] = fmaxf(v, 0.0f);
      }
    }
  }
}

extern "C" void kernel_launch(void* const* d_in, const int* in_sizes, int n_in,
                              void* d_out, int out_size, void* d_ws, size_t ws_size,
                              hipStream_t stream) {
  const float* x      = (const float*)d_in[0];
  const int*   src    = (const int*)d_in[1];
  const int*   dst    = (const int*)d_in[2];
  const float* bases  = (const float*)d_in[3];
  const float* w_comp = (const float*)d_in[4];
  const float* loop_w = (const float*)d_in[5];
  const float* h_bias = (const float*)d_in[6];
  const float* gamma  = (const float*)d_in[7];
  const float* beta   = (const float*)d_in[8];
  float* out = (float*)d_out;

  char* ws = (char*)d_ws;
  unsigned short* A  = (unsigned short*)ws;                // 153,600,000 B
  unsigned short* Bt = (unsigned short*)(ws + 153600000);  //     393,216 B
  int* cnt     = (int*)(ws + 153993216);                   //     400,000 B
  int* edgebuf = (int*)(ws + 154393216);                   //  12,800,000 B
  // total 167,193,216 B

  hipMemsetAsync(cnt, 0, 400000, stream);

  prep<<<28893, 256, 0, stream>>>(x, bases, loop_w, src, dst, A, Bt, cnt, edgebuf);
  agg_edges<<<12500, 256, 0, stream>>>(edgebuf, cnt, w_comp, A);
  gemm_ln<<<(NN + BM - 1) / BM, 256, 0, stream>>>(A, Bt, h_bias, gamma, beta, out);
}